// Round 1
// baseline (738.791 us; speedup 1.0000x reference)
//
#include <hip/hip_runtime.h>
#include <hip/hip_bf16.h>

#define D_IN 256
#define D_OUT 128
#define LN_EPS 1e-5f

typedef short bf16x8 __attribute__((ext_vector_type(8)));
typedef float f32x4 __attribute__((ext_vector_type(4)));
typedef unsigned short ushort_t;

__device__ __forceinline__ float b2f(ushort_t u) {
    union { unsigned int i; float f; } v; v.i = (unsigned int)u << 16; return v.f;
}
__device__ __forceinline__ ushort_t f2b(float f) {
    __hip_bfloat16 h = __float2bfloat16(f);
    return *reinterpret_cast<ushort_t*>(&h);
}

// ---------------- Kernel 0: pack+transpose f32 weights into bf16 Wt[n][k]; also zero ncnt
__global__ void k_transpose(const float* __restrict__ w, const float* __restrict__ rw,
                            ushort_t* __restrict__ wt, int* __restrict__ ncnt, int n_nodes) {
    int idx = blockIdx.x * 256 + threadIdx.x;   // 65536 total
    int n = idx >> 8, k = idx & 255;
    float v = (n < 128) ? w[k * 128 + n] : rw[k * 128 + (n - 128)];
    wt[idx] = f2b(v);
    if (idx < n_nodes) ncnt[idx] = 0;
    int i2 = idx + 65536;
    if (i2 < n_nodes) ncnt[i2] = 0;
}

// ---------------- Kernel 1: dual GEMM (bf16 MFMA internally, f32 in/out) -- unchanged
__launch_bounds__(256)
__global__ void k_gemm(const float* __restrict__ x, const ushort_t* __restrict__ wt,
                       const float* __restrict__ bias, const float* __restrict__ res_b,
                       ushort_t* __restrict__ support, float* __restrict__ out, int n_nodes) {
    __shared__ ushort_t As[64 * 40];
    __shared__ ushort_t Bs[256 * 40];

    const int tid = threadIdx.x;
    const int m0 = blockIdx.x * 64;
    const int wv = tid >> 6, lane = tid & 63;
    const int lm = lane & 15, quad = lane >> 4;
    const int mh = wv >> 1;
    const int nh = wv & 1;

    f32x4 acc[2][8];
#pragma unroll
    for (int i = 0; i < 2; i++)
#pragma unroll
        for (int j = 0; j < 8; j++) acc[i][j] = 0.0f;

    const int arow = tid >> 2, aseg = tid & 3;
    const bool arow_ok = (m0 + arow) < n_nodes;
    const float* xrow = x + (long)(m0 + arow) * D_IN + aseg * 8;

    for (int kc = 0; kc < 8; kc++) {
        __syncthreads();
        {
            bf16x8 av = {0, 0, 0, 0, 0, 0, 0, 0};
            if (arow_ok) {
                f32x4 p0 = *(const f32x4*)(xrow + kc * 32);
                f32x4 p1 = *(const f32x4*)(xrow + kc * 32 + 4);
#pragma unroll
                for (int j = 0; j < 4; j++) { av[j] = (short)f2b(p0[j]); av[4 + j] = (short)f2b(p1[j]); }
            }
            *(bf16x8*)(&As[arow * 40 + aseg * 8]) = av;
        }
#pragma unroll
        for (int i = 0; i < 4; i++) {
            int n = (tid >> 2) + i * 64;
            bf16x8 v = *(const bf16x8*)(wt + n * 256 + kc * 32 + aseg * 8);
            *(bf16x8*)(&Bs[n * 40 + aseg * 8]) = v;
        }
        __syncthreads();

        bf16x8 afr0 = *(const bf16x8*)(&As[(mh * 32 + lm) * 40 + quad * 8]);
        bf16x8 afr1 = *(const bf16x8*)(&As[(mh * 32 + 16 + lm) * 40 + quad * 8]);
#pragma unroll
        for (int nt = 0; nt < 8; nt++) {
            bf16x8 bfr = *(const bf16x8*)(&Bs[(nh * 128 + nt * 16 + lm) * 40 + quad * 8]);
            acc[0][nt] = __builtin_amdgcn_mfma_f32_16x16x32_bf16(afr0, bfr, acc[0][nt], 0, 0, 0);
            acc[1][nt] = __builtin_amdgcn_mfma_f32_16x16x32_bf16(afr1, bfr, acc[1][nt], 0, 0, 0);
        }
    }

#pragma unroll
    for (int i = 0; i < 2; i++) {
#pragma unroll
        for (int nt = 0; nt < 8; nt++) {
            int col = nh * 128 + nt * 16 + lm;
#pragma unroll
            for (int r = 0; r < 4; r++) {
                int node = m0 + mh * 32 + i * 16 + quad * 4 + r;
                if (node >= n_nodes) continue;
                float v = acc[i][nt][r];
                if (col < 128) {
                    support[(long)node * 128 + col] = f2b(v);
                } else {
                    int c2 = col - 128;
                    float t = v + res_b[c2];
                    t = t > 0.0f ? t : 0.0f;
                    out[(long)node * 128 + c2] = t + bias[c2];
                }
            }
        }
    }
}

// ---------------- Kernel 2: per-node histogram via global atomics (ncnt pre-zeroed)
__launch_bounds__(256)
__global__ void k_hist(const int* __restrict__ ei, int* __restrict__ ncnt, int E) {
    int i = blockIdx.x * blockDim.x + threadIdx.x;
    int st = gridDim.x * blockDim.x;
    for (int e = i; e < E; e += st)
        atomicAdd(&ncnt[ei[E + e]], 1);
}

// ---------------- Kernel 3a: block-level scan of ncnt (1024 elems / block of 256 thr)
__launch_bounds__(256)
__global__ void k_scanA(const int* __restrict__ ncnt, int* __restrict__ poff,
                        int* __restrict__ bsum, int n) {
    __shared__ int sh[256];
    int b = blockIdx.x, t = threadIdx.x;
    int e0 = b * 1024 + t * 4;
    int v0 = (e0 + 0 < n) ? ncnt[e0 + 0] : 0;
    int v1 = (e0 + 1 < n) ? ncnt[e0 + 1] : 0;
    int v2 = (e0 + 2 < n) ? ncnt[e0 + 2] : 0;
    int v3 = (e0 + 3 < n) ? ncnt[e0 + 3] : 0;
    int s3 = v0 + v1 + v2 + v3;
    sh[t] = s3;
    __syncthreads();
    for (int off = 1; off < 256; off <<= 1) {
        int x = sh[t]; int add = (t >= off) ? sh[t - off] : 0;
        __syncthreads(); sh[t] = x + add; __syncthreads();
    }
    int excl = sh[t] - s3;
    if (e0 + 0 < n) poff[e0 + 0] = excl;
    if (e0 + 1 < n) poff[e0 + 1] = excl + v0;
    if (e0 + 2 < n) poff[e0 + 2] = excl + v0 + v1;
    if (e0 + 3 < n) poff[e0 + 3] = excl + v0 + v1 + v2;
    if (t == 255) bsum[b] = sh[255];
}

// ---------------- Kernel 3b: scan block sums (<=256 blocks); also offs[N]=E
__launch_bounds__(256)
__global__ void k_scanB(const int* __restrict__ bsum, int* __restrict__ bbase,
                        int* __restrict__ offs, int nb, int n, int E) {
    __shared__ int sh[256];
    int t = threadIdx.x;
    int v = (t < nb) ? bsum[t] : 0;
    sh[t] = v;
    __syncthreads();
    for (int off = 1; off < 256; off <<= 1) {
        int x = sh[t]; int add = (t >= off) ? sh[t - off] : 0;
        __syncthreads(); sh[t] = x + add; __syncthreads();
    }
    bbase[t] = sh[t] - v;
    if (t == 0) offs[n] = E;
}

// ---------------- Kernel 3c: finalize offs + init scatter cursors
__launch_bounds__(256)
__global__ void k_scanC(const int* __restrict__ poff, const int* __restrict__ bbase,
                        int* __restrict__ offs, int* __restrict__ ncur, int n) {
    int i = blockIdx.x * 256 + threadIdx.x;
    if (i < n) {
        int o = poff[i] + bbase[i >> 10];
        offs[i] = o;
        ncur[i] = o;
    }
}

// ---------------- Kernel 4: one-pass scatter into dst-sorted records {src, w_f32}
__launch_bounds__(256)
__global__ void k_scatter(const int* __restrict__ ei, const float* __restrict__ ew,
                          int* __restrict__ ncur, int2* __restrict__ recs, int E) {
    int i = blockIdx.x * blockDim.x + threadIdx.x;
    int st = gridDim.x * blockDim.x;
    for (int e = i; e < E; e += st) {
        int src = ei[e];
        int dst = ei[E + e];
        float w = ew[e];
        int pos = atomicAdd(&ncur[dst], 1);
        int2 r; r.x = src; r.y = __float_as_int(w);
        recs[pos] = r;
    }
}

// ---------------- Kernel 5: gather-aggregate + residual + LayerNorm (wave per node)
__launch_bounds__(256)
__global__ void k_agg_ln(const ushort_t* __restrict__ support, const int* __restrict__ offs,
                         const int2* __restrict__ recs,
                         const float* __restrict__ gamma, const float* __restrict__ beta,
                         float* __restrict__ out, int n_nodes) {
    int gw = (int)((blockIdx.x * blockDim.x + threadIdx.x) >> 6);
    int lane = threadIdx.x & 63;
    int nw = (int)((gridDim.x * blockDim.x) >> 6);
    float g0 = gamma[lane * 2], g1 = gamma[lane * 2 + 1];
    float b0 = beta[lane * 2], b1 = beta[lane * 2 + 1];
    const ushort_t* sup_lane = support + lane * 2;

    for (int node = gw; node < n_nodes; node += nw) {
        int start = offs[node], end = offs[node + 1];
        float ax = 0.0f, ay = 0.0f;
        for (int base = start; base < end; base += 64) {
            int n = end - base; if (n > 64) n = 64;
            int key = 0, wb = 0;
            if (lane < n) {
                int2 r = recs[base + lane];
                key = r.x; wb = r.y;
            }
            int j = 0;
            for (; j + 8 <= n; j += 8) {
                unsigned int v[8]; float w[8];
#pragma unroll
                for (int u = 0; u < 8; u++) {
                    int s = __builtin_amdgcn_readlane(key, j + u);
                    w[u] = __int_as_float(__builtin_amdgcn_readlane(wb, j + u));
                    v[u] = *(const unsigned int*)(sup_lane + (long)s * 128);
                }
#pragma unroll
                for (int u = 0; u < 8; u++) {
                    ax += w[u] * b2f((ushort_t)(v[u] & 0xffffu));
                    ay += w[u] * b2f((ushort_t)(v[u] >> 16));
                }
            }
            for (; j < n; j++) {
                int s = __builtin_amdgcn_readlane(key, j);
                float wj = __int_as_float(__builtin_amdgcn_readlane(wb, j));
                unsigned int v = *(const unsigned int*)(sup_lane + (long)s * 128);
                ax += wj * b2f((ushort_t)(v & 0xffffu));
                ay += wj * b2f((ushort_t)(v >> 16));
            }
        }
        float2 r = *(const float2*)(out + (long)node * 128 + lane * 2);
        float tx = ax + r.x, ty = ay + r.y;
        float s = tx + ty;
        float ss = tx * tx + ty * ty;
#pragma unroll
        for (int off = 1; off < 64; off <<= 1) {
            s += __shfl_xor(s, off, 64);
            ss += __shfl_xor(ss, off, 64);
        }
        float mean = s * (1.0f / 128.0f);
        float var = ss * (1.0f / 128.0f) - mean * mean;
        float rstd = rsqrtf(var + LN_EPS);
        float2 o;
        o.x = (tx - mean) * rstd * g0 + b0;
        o.y = (ty - mean) * rstd * g1 + b1;
        *(float2*)(out + (long)node * 128 + lane * 2) = o;
    }
}

extern "C" void kernel_launch(void* const* d_in, const int* in_sizes, int n_in,
                              void* d_out, int out_size, void* d_ws, size_t ws_size,
                              hipStream_t stream) {
    const float* x      = (const float*)d_in[0];
    const float* weight = (const float*)d_in[1];
    const float* bias   = (const float*)d_in[2];
    const float* res_w  = (const float*)d_in[3];
    const float* res_b  = (const float*)d_in[4];
    const float* gamma  = (const float*)d_in[5];
    const float* beta   = (const float*)d_in[6];
    const float* ew     = (const float*)d_in[7];
    const int*   ei     = (const int*)d_in[8];

    const int E = in_sizes[7];
    const int n_nodes = in_sizes[0] / D_IN;
    float* out = (float*)d_out;

    // workspace layout (256B-aligned), total ~53 MB
    char* ws = (char*)d_ws;
    size_t off = 0;
    auto alloc = [&](size_t bytes) { void* p = ws + off; off = (off + bytes + 255) & ~(size_t)255; return p; };
    ushort_t* wt      = (ushort_t*)alloc(256 * 256 * 2);                 // 128 KB
    ushort_t* support = (ushort_t*)alloc((size_t)n_nodes * 128 * 2);     // 25.6 MB
    int* ncnt         = (int*)alloc((size_t)n_nodes * 4);                // 400 KB
    int* poff         = (int*)alloc((size_t)n_nodes * 4);                // 400 KB
    int* bsum         = (int*)alloc(256 * 4);
    int* bbase        = (int*)alloc(256 * 4);
    int* offs         = (int*)alloc((size_t)(n_nodes + 1) * 4);          // 400 KB
    int* ncur         = (int*)alloc((size_t)n_nodes * 4);                // 400 KB
    int2* recs        = (int2*)alloc((size_t)E * 8);                     // 25.6 MB

    int nbA = (n_nodes + 1023) / 1024;   // <= 256 for n_nodes <= 262144

    k_transpose<<<256, 256, 0, stream>>>(weight, res_w, wt, ncnt, n_nodes);
    k_gemm<<<(n_nodes + 63) / 64, 256, 0, stream>>>(x, wt, bias, res_b, support, out, n_nodes);
    k_hist<<<2048, 256, 0, stream>>>(ei, ncnt, E);
    k_scanA<<<nbA, 256, 0, stream>>>(ncnt, poff, bsum, n_nodes);
    k_scanB<<<1, 256, 0, stream>>>(bsum, bbase, offs, nbA, n_nodes, E);
    k_scanC<<<(n_nodes + 255) / 256, 256, 0, stream>>>(poff, bbase, offs, ncur, n_nodes);
    k_scatter<<<2048, 256, 0, stream>>>(ei, ew, ncur, recs, E);
    k_agg_ln<<<4096, 256, 0, stream>>>(support, offs, recs, gamma, beta, out, n_nodes);
}

// Round 4
// 509.438 us; speedup vs baseline: 1.4502x; 1.4502x over previous
//
#include <hip/hip_runtime.h>
#include <hip/hip_bf16.h>

#define D_IN 256
#define D_OUT 128
#define LN_EPS 1e-5f
#define NBUCK 256          // coarse buckets, bucket = dst >> 9 (512 nodes each)
#define NCHUNK 256         // edge chunks (one block each) in count/part

typedef short bf16x8 __attribute__((ext_vector_type(8)));
typedef float f32x4 __attribute__((ext_vector_type(4)));
typedef unsigned short ushort_t;

__device__ __forceinline__ float b2f(ushort_t u) {
    union { unsigned int i; float f; } v; v.i = (unsigned int)u << 16; return v.f;
}
__device__ __forceinline__ ushort_t f2b(float f) {
    __hip_bfloat16 h = __float2bfloat16(f);
    return *reinterpret_cast<ushort_t*>(&h);
}

// ---------------- Kernel 0: pack+transpose f32 weights into bf16 Wt[n][k], n = [W | res_w] cols
__global__ void k_transpose(const float* __restrict__ w, const float* __restrict__ rw,
                            ushort_t* __restrict__ wt) {
    int idx = blockIdx.x * 256 + threadIdx.x;   // 65536 total
    int n = idx >> 8, k = idx & 255;
    float v = (n < 128) ? w[k * 128 + n] : rw[k * 128 + (n - 128)];
    wt[idx] = f2b(v);
}

// ---------------- Kernel 1: dual GEMM (bf16 MFMA internally, f32 in/out)
__launch_bounds__(256)
__global__ void k_gemm(const float* __restrict__ x, const ushort_t* __restrict__ wt,
                       const float* __restrict__ bias, const float* __restrict__ res_b,
                       ushort_t* __restrict__ support, float* __restrict__ out, int n_nodes) {
    __shared__ ushort_t As[64 * 40];
    __shared__ ushort_t Bs[256 * 40];

    const int tid = threadIdx.x;
    const int m0 = blockIdx.x * 64;
    const int wv = tid >> 6, lane = tid & 63;
    const int lm = lane & 15, quad = lane >> 4;
    const int mh = wv >> 1;
    const int nh = wv & 1;

    f32x4 acc[2][8];
#pragma unroll
    for (int i = 0; i < 2; i++)
#pragma unroll
        for (int j = 0; j < 8; j++) acc[i][j] = 0.0f;

    const int arow = tid >> 2, aseg = tid & 3;
    const bool arow_ok = (m0 + arow) < n_nodes;
    const float* xrow = x + (long)(m0 + arow) * D_IN + aseg * 8;

    for (int kc = 0; kc < 8; kc++) {
        __syncthreads();
        {
            bf16x8 av = {0, 0, 0, 0, 0, 0, 0, 0};
            if (arow_ok) {
                f32x4 p0 = *(const f32x4*)(xrow + kc * 32);
                f32x4 p1 = *(const f32x4*)(xrow + kc * 32 + 4);
#pragma unroll
                for (int j = 0; j < 4; j++) { av[j] = (short)f2b(p0[j]); av[4 + j] = (short)f2b(p1[j]); }
            }
            *(bf16x8*)(&As[arow * 40 + aseg * 8]) = av;
        }
#pragma unroll
        for (int i = 0; i < 4; i++) {
            int n = (tid >> 2) + i * 64;
            bf16x8 v = *(const bf16x8*)(wt + n * 256 + kc * 32 + aseg * 8);
            *(bf16x8*)(&Bs[n * 40 + aseg * 8]) = v;
        }
        __syncthreads();

        bf16x8 afr0 = *(const bf16x8*)(&As[(mh * 32 + lm) * 40 + quad * 8]);
        bf16x8 afr1 = *(const bf16x8*)(&As[(mh * 32 + 16 + lm) * 40 + quad * 8]);
#pragma unroll
        for (int nt = 0; nt < 8; nt++) {
            bf16x8 bfr = *(const bf16x8*)(&Bs[(nh * 128 + nt * 16 + lm) * 40 + quad * 8]);
            acc[0][nt] = __builtin_amdgcn_mfma_f32_16x16x32_bf16(afr0, bfr, acc[0][nt], 0, 0, 0);
            acc[1][nt] = __builtin_amdgcn_mfma_f32_16x16x32_bf16(afr1, bfr, acc[1][nt], 0, 0, 0);
        }
    }

#pragma unroll
    for (int i = 0; i < 2; i++) {
#pragma unroll
        for (int nt = 0; nt < 8; nt++) {
            int col = nh * 128 + nt * 16 + lm;
#pragma unroll
            for (int r = 0; r < 4; r++) {
                int node = m0 + mh * 32 + i * 16 + quad * 4 + r;
                if (node >= n_nodes) continue;
                float v = acc[i][nt][r];
                if (col < 128) {
                    support[(long)node * 128 + col] = f2b(v);
                } else {
                    int c2 = col - 128;
                    float t = v + res_b[c2];
                    t = t > 0.0f ? t : 0.0f;
                    out[(long)node * 128 + c2] = t + bias[c2];
                }
            }
        }
    }
}

// ---------------- Kernel 2: per-chunk bucket histogram -> cntmat[bucket][chunk]
__launch_bounds__(256)
__global__ void k_count(const int* __restrict__ ei, int* __restrict__ cntmat, int E, int chunk) {
    __shared__ int h[NBUCK];
    int c = blockIdx.x, t = threadIdx.x;
    h[t] = 0;
    __syncthreads();
    int lo = c * chunk, hi = min(lo + chunk, E);
    for (int e = lo + t; e < hi; e += 256)
        atomicAdd(&h[(unsigned)ei[E + e] >> 9], 1);
    __syncthreads();
    cntmat[t * NCHUNK + c] = h[t];
}

// ---------------- Kernel 3a: scan each bucket row of cntmat (exclusive), rowsum out
__launch_bounds__(256)
__global__ void k_scan1(int* __restrict__ cntmat, int* __restrict__ rowsum) {
    __shared__ int sh[256];
    int b = blockIdx.x, t = threadIdx.x;
    int v = cntmat[b * NCHUNK + t];
    sh[t] = v;
    __syncthreads();
    for (int off = 1; off < 256; off <<= 1) {
        int x = sh[t]; int add = (t >= off) ? sh[t - off] : 0;
        __syncthreads(); sh[t] = x + add; __syncthreads();
    }
    cntmat[b * NCHUNK + t] = sh[t] - v;
    if (t == 255) rowsum[b] = sh[255];
}

// ---------------- Kernel 3b: scan bucket sums -> bucket_base; also offs[N]=E
__launch_bounds__(256)
__global__ void k_scan2(const int* __restrict__ rowsum, int* __restrict__ bucket_base,
                        int* __restrict__ offs, int n_nodes, int E) {
    __shared__ int sh[256];
    int t = threadIdx.x;
    int v = rowsum[t];
    sh[t] = v;
    __syncthreads();
    for (int off = 1; off < 256; off <<= 1) {
        int x = sh[t]; int add = (t >= off) ? sh[t - off] : 0;
        __syncthreads(); sh[t] = x + add; __syncthreads();
    }
    bucket_base[t] = sh[t] - v;
    if (t == 255) bucket_base[256] = sh[255];
    if (t == 0) offs[n_nodes] = E;
}

// ---------------- Kernel 4: partition edges into buckets (block-private sub-regions)
// pk = dl<<17 | src  (4B), pw = weight bf16 (2B)
__launch_bounds__(256)
__global__ void k_part(const int* __restrict__ ei, const float* __restrict__ ew,
                       const int* __restrict__ cntmat, const int* __restrict__ bucket_base,
                       int* __restrict__ pk, ushort_t* __restrict__ pw, int E, int chunk) {
    __shared__ int cur[NBUCK];
    int c = blockIdx.x, t = threadIdx.x;
    cur[t] = bucket_base[t] + cntmat[t * NCHUNK + c];
    __syncthreads();
    int lo = c * chunk, hi = min(lo + chunk, E);
    for (int e = lo + t; e < hi; e += 256) {
        int src = ei[e];
        int dst = ei[E + e];
        float w = ew[e];
        int b = (unsigned)dst >> 9;
        int pos = atomicAdd(&cur[b], 1);
        pk[pos] = src | ((dst & 511) << 17);
        pw[pos] = f2b(w);
    }
}

// ---------------- Kernel 5: per-bucket node-sort: write sorted records + offs
__launch_bounds__(256)
__global__ void k_build(const int* __restrict__ pk, const ushort_t* __restrict__ pw,
                        const int* __restrict__ bucket_base, int* __restrict__ sk,
                        ushort_t* __restrict__ sw, int* __restrict__ offs, int n_nodes) {
    __shared__ int h[512];
    __shared__ int psum[256];
    int b = blockIdx.x, t = threadIdx.x;
    int start = bucket_base[b], end = bucket_base[b + 1];
    h[t] = 0; h[t + 256] = 0;
    __syncthreads();
    for (int i = start + t; i < end; i += 256)
        atomicAdd(&h[(unsigned)pk[i] >> 17], 1);
    __syncthreads();
    int h0 = h[2 * t], h1 = h[2 * t + 1];
    int p = h0 + h1;
    psum[t] = p;
    __syncthreads();
    for (int off = 1; off < 256; off <<= 1) {
        int x = psum[t]; int add = (t >= off) ? psum[t - off] : 0;
        __syncthreads(); psum[t] = x + add; __syncthreads();
    }
    int e0 = psum[t] - p;
    int e1 = e0 + h0;
    h[2 * t] = e0; h[2 * t + 1] = e1;
    int node0 = b * 512 + 2 * t;
    if (node0 < n_nodes) offs[node0] = start + e0;
    if (node0 + 1 < n_nodes) offs[node0 + 1] = start + e1;
    __syncthreads();
    for (int i = start + t; i < end; i += 256) {
        int key = pk[i];
        int dl = (unsigned)key >> 17;
        int pos = start + atomicAdd(&h[dl], 1);
        sk[pos] = key;
        sw[pos] = pw[i];
    }
}

// ---------------- Kernel 6: gather-aggregate + residual + LayerNorm (wave per node)
__launch_bounds__(256)
__global__ void k_agg_ln(const ushort_t* __restrict__ support, const int* __restrict__ offs,
                         const int* __restrict__ sk, const ushort_t* __restrict__ sw,
                         const float* __restrict__ gamma, const float* __restrict__ beta,
                         float* __restrict__ out, int n_nodes) {
    int gw = (int)((blockIdx.x * blockDim.x + threadIdx.x) >> 6);
    int lane = threadIdx.x & 63;
    int nw = (int)((gridDim.x * blockDim.x) >> 6);
    float g0 = gamma[lane * 2], g1 = gamma[lane * 2 + 1];
    float b0 = beta[lane * 2], b1 = beta[lane * 2 + 1];
    const ushort_t* sup_lane = support + lane * 2;

    for (int node = gw; node < n_nodes; node += nw) {
        int start = offs[node], end = offs[node + 1];
        float ax = 0.0f, ay = 0.0f;
        for (int base = start; base < end; base += 64) {
            int n = end - base; if (n > 64) n = 64;
            int key = 0, wb = 0;
            if (lane < n) {
                key = sk[base + lane];
                wb = (int)sw[base + lane];
            }
            int j = 0;
            for (; j + 8 <= n; j += 8) {
                unsigned int v[8]; float w[8];
#pragma unroll
                for (int u = 0; u < 8; u++) {
                    int s = __builtin_amdgcn_readlane(key, j + u) & 131071;
                    w[u] = b2f((ushort_t)__builtin_amdgcn_readlane(wb, j + u));
                    v[u] = *(const unsigned int*)(sup_lane + (long)s * 128);
                }
#pragma unroll
                for (int u = 0; u < 8; u++) {
                    ax += w[u] * b2f((ushort_t)(v[u] & 0xffffu));
                    ay += w[u] * b2f((ushort_t)(v[u] >> 16));
                }
            }
            for (; j < n; j++) {
                int s = __builtin_amdgcn_readlane(key, j) & 131071;
                float wj = b2f((ushort_t)__builtin_amdgcn_readlane(wb, j));
                unsigned int v = *(const unsigned int*)(sup_lane + (long)s * 128);
                ax += wj * b2f((ushort_t)(v & 0xffffu));
                ay += wj * b2f((ushort_t)(v >> 16));
            }
        }
        float2 r = *(const float2*)(out + (long)node * 128 + lane * 2);
        float tx = ax + r.x, ty = ay + r.y;
        float s = tx + ty;
        float ss = tx * tx + ty * ty;
#pragma unroll
        for (int off = 1; off < 64; off <<= 1) {
            s += __shfl_xor(s, off, 64);
            ss += __shfl_xor(ss, off, 64);
        }
        float mean = s * (1.0f / 128.0f);
        float var = ss * (1.0f / 128.0f) - mean * mean;
        float rstd = rsqrtf(var + LN_EPS);
        float2 o;
        o.x = (tx - mean) * rstd * g0 + b0;
        o.y = (ty - mean) * rstd * g1 + b1;
        *(float2*)(out + (long)node * 128 + lane * 2) = o;
    }
}

extern "C" void kernel_launch(void* const* d_in, const int* in_sizes, int n_in,
                              void* d_out, int out_size, void* d_ws, size_t ws_size,
                              hipStream_t stream) {
    const float* x      = (const float*)d_in[0];
    const float* weight = (const float*)d_in[1];
    const float* bias   = (const float*)d_in[2];
    const float* res_w  = (const float*)d_in[3];
    const float* res_b  = (const float*)d_in[4];
    const float* gamma  = (const float*)d_in[5];
    const float* beta   = (const float*)d_in[6];
    const float* ew     = (const float*)d_in[7];
    const int*   ei     = (const int*)d_in[8];

    const int E = in_sizes[7];
    const int n_nodes = in_sizes[0] / D_IN;
    const int chunk = (E + NCHUNK - 1) / NCHUNK;
    float* out = (float*)d_out;

    // workspace layout (256B-aligned), total ~65 MB (identical to round-0 verified layout)
    char* ws = (char*)d_ws;
    size_t off = 0;
    auto alloc = [&](size_t bytes) { void* p = ws + off; off = (off + bytes + 255) & ~(size_t)255; return p; };
    ushort_t* wt      = (ushort_t*)alloc(256 * 256 * 2);                 // 128 KB
    ushort_t* support = (ushort_t*)alloc((size_t)n_nodes * 128 * 2);     // 25.6 MB
    int* cntmat       = (int*)alloc((size_t)NBUCK * NCHUNK * 4);         // 256 KB
    int* rowsum       = (int*)alloc(NBUCK * 4);
    int* bucket_base  = (int*)alloc((NBUCK + 1) * 4);
    int* offs         = (int*)alloc((size_t)(n_nodes + 1) * 4);          // 400 KB
    int* pk           = (int*)alloc((size_t)E * 4);                      // 12.8 MB
    ushort_t* pw      = (ushort_t*)alloc((size_t)E * 2);                 // 6.4 MB
    int* sk           = (int*)alloc((size_t)E * 4);                      // 12.8 MB
    ushort_t* sw      = (ushort_t*)alloc((size_t)E * 2);                 // 6.4 MB

    k_transpose<<<256, 256, 0, stream>>>(weight, res_w, wt);
    k_gemm<<<(n_nodes + 63) / 64, 256, 0, stream>>>(x, wt, bias, res_b, support, out, n_nodes);
    k_count<<<NCHUNK, 256, 0, stream>>>(ei, cntmat, E, chunk);
    k_scan1<<<NBUCK, 256, 0, stream>>>(cntmat, rowsum);
    k_scan2<<<1, 256, 0, stream>>>(rowsum, bucket_base, offs, n_nodes, E);
    k_part<<<NCHUNK, 256, 0, stream>>>(ei, ew, cntmat, bucket_base, pk, pw, E, chunk);
    k_build<<<NBUCK, 256, 0, stream>>>(pk, pw, bucket_base, sk, sw, offs, n_nodes);
    k_agg_ln<<<4096, 256, 0, stream>>>(support, offs, sk, sw, gamma, beta, out, n_nodes);
}

// Round 5
// 509.432 us; speedup vs baseline: 1.4502x; 1.0000x over previous
//
#include <hip/hip_runtime.h>
#include <hip/hip_bf16.h>

#define D_IN 256
#define D_OUT 128
#define LN_EPS 1e-5f
#define NBUCK 256          // coarse buckets, bucket = dst >> 9 (512 nodes each)
#define NCHUNK 256         // edge chunks (one block each) in count/part

typedef short bf16x8 __attribute__((ext_vector_type(8)));
typedef float f32x4 __attribute__((ext_vector_type(4)));
typedef unsigned short ushort_t;

__device__ __forceinline__ float b2f(ushort_t u) {
    union { unsigned int i; float f; } v; v.i = (unsigned int)u << 16; return v.f;
}
__device__ __forceinline__ ushort_t f2b(float f) {
    __hip_bfloat16 h = __float2bfloat16(f);
    return *reinterpret_cast<ushort_t*>(&h);
}

// ---------------- Kernel 0: pack+transpose f32 weights into bf16 Wt[n][k], n = [W | res_w] cols
__global__ void k_transpose(const float* __restrict__ w, const float* __restrict__ rw,
                            ushort_t* __restrict__ wt) {
    int idx = blockIdx.x * 256 + threadIdx.x;   // 65536 total
    int n = idx >> 8, k = idx & 255;
    float v = (n < 128) ? w[k * 128 + n] : rw[k * 128 + (n - 128)];
    wt[idx] = f2b(v);
}

// ---------------- Kernel 1: dual GEMM (bf16 MFMA internally, f32 in/out)
__launch_bounds__(256)
__global__ void k_gemm(const float* __restrict__ x, const ushort_t* __restrict__ wt,
                       const float* __restrict__ bias, const float* __restrict__ res_b,
                       ushort_t* __restrict__ support, float* __restrict__ out, int n_nodes) {
    __shared__ ushort_t As[64 * 40];
    __shared__ ushort_t Bs[256 * 40];

    const int tid = threadIdx.x;
    const int m0 = blockIdx.x * 64;
    const int wv = tid >> 6, lane = tid & 63;
    const int lm = lane & 15, quad = lane >> 4;
    const int mh = wv >> 1;
    const int nh = wv & 1;

    f32x4 acc[2][8];
#pragma unroll
    for (int i = 0; i < 2; i++)
#pragma unroll
        for (int j = 0; j < 8; j++) acc[i][j] = 0.0f;

    const int arow = tid >> 2, aseg = tid & 3;
    const bool arow_ok = (m0 + arow) < n_nodes;
    const float* xrow = x + (long)(m0 + arow) * D_IN + aseg * 8;

    for (int kc = 0; kc < 8; kc++) {
        __syncthreads();
        {
            bf16x8 av = {0, 0, 0, 0, 0, 0, 0, 0};
            if (arow_ok) {
                f32x4 p0 = *(const f32x4*)(xrow + kc * 32);
                f32x4 p1 = *(const f32x4*)(xrow + kc * 32 + 4);
#pragma unroll
                for (int j = 0; j < 4; j++) { av[j] = (short)f2b(p0[j]); av[4 + j] = (short)f2b(p1[j]); }
            }
            *(bf16x8*)(&As[arow * 40 + aseg * 8]) = av;
        }
#pragma unroll
        for (int i = 0; i < 4; i++) {
            int n = (tid >> 2) + i * 64;
            bf16x8 v = *(const bf16x8*)(wt + n * 256 + kc * 32 + aseg * 8);
            *(bf16x8*)(&Bs[n * 40 + aseg * 8]) = v;
        }
        __syncthreads();

        bf16x8 afr0 = *(const bf16x8*)(&As[(mh * 32 + lm) * 40 + quad * 8]);
        bf16x8 afr1 = *(const bf16x8*)(&As[(mh * 32 + 16 + lm) * 40 + quad * 8]);
#pragma unroll
        for (int nt = 0; nt < 8; nt++) {
            bf16x8 bfr = *(const bf16x8*)(&Bs[(nh * 128 + nt * 16 + lm) * 40 + quad * 8]);
            acc[0][nt] = __builtin_amdgcn_mfma_f32_16x16x32_bf16(afr0, bfr, acc[0][nt], 0, 0, 0);
            acc[1][nt] = __builtin_amdgcn_mfma_f32_16x16x32_bf16(afr1, bfr, acc[1][nt], 0, 0, 0);
        }
    }

#pragma unroll
    for (int i = 0; i < 2; i++) {
#pragma unroll
        for (int nt = 0; nt < 8; nt++) {
            int col = nh * 128 + nt * 16 + lm;
#pragma unroll
            for (int r = 0; r < 4; r++) {
                int node = m0 + mh * 32 + i * 16 + quad * 4 + r;
                if (node >= n_nodes) continue;
                float v = acc[i][nt][r];
                if (col < 128) {
                    support[(long)node * 128 + col] = f2b(v);
                } else {
                    int c2 = col - 128;
                    float t = v + res_b[c2];
                    t = t > 0.0f ? t : 0.0f;
                    out[(long)node * 128 + c2] = t + bias[c2];
                }
            }
        }
    }
}

// ---------------- Kernel 2: per-chunk bucket histogram -> cntmat[bucket][chunk]
__launch_bounds__(256)
__global__ void k_count(const int* __restrict__ ei, int* __restrict__ cntmat, int E, int chunk) {
    __shared__ int h[NBUCK];
    int c = blockIdx.x, t = threadIdx.x;
    h[t] = 0;
    __syncthreads();
    int lo = c * chunk, hi = min(lo + chunk, E);
    for (int e = lo + t; e < hi; e += 256)
        atomicAdd(&h[(unsigned)ei[E + e] >> 9], 1);
    __syncthreads();
    cntmat[t * NCHUNK + c] = h[t];
}

// ---------------- Kernel 3a: scan each bucket row of cntmat (exclusive), rowsum out
__launch_bounds__(256)
__global__ void k_scan1(int* __restrict__ cntmat, int* __restrict__ rowsum) {
    __shared__ int sh[256];
    int b = blockIdx.x, t = threadIdx.x;
    int v = cntmat[b * NCHUNK + t];
    sh[t] = v;
    __syncthreads();
    for (int off = 1; off < 256; off <<= 1) {
        int x = sh[t]; int add = (t >= off) ? sh[t - off] : 0;
        __syncthreads(); sh[t] = x + add; __syncthreads();
    }
    cntmat[b * NCHUNK + t] = sh[t] - v;
    if (t == 255) rowsum[b] = sh[255];
}

// ---------------- Kernel 3b: scan bucket sums -> bucket_base; also offs[N]=E
__launch_bounds__(256)
__global__ void k_scan2(const int* __restrict__ rowsum, int* __restrict__ bucket_base,
                        int* __restrict__ offs, int n_nodes, int E) {
    __shared__ int sh[256];
    int t = threadIdx.x;
    int v = rowsum[t];
    sh[t] = v;
    __syncthreads();
    for (int off = 1; off < 256; off <<= 1) {
        int x = sh[t]; int add = (t >= off) ? sh[t - off] : 0;
        __syncthreads(); sh[t] = x + add; __syncthreads();
    }
    bucket_base[t] = sh[t] - v;
    if (t == 255) bucket_base[256] = sh[255];
    if (t == 0) offs[n_nodes] = E;
}

// ---------------- Kernel 4: partition edges into buckets (block-private sub-regions)
// pk = dl<<17 | src  (4B), pw = weight bf16 (2B)
__launch_bounds__(256)
__global__ void k_part(const int* __restrict__ ei, const float* __restrict__ ew,
                       const int* __restrict__ cntmat, const int* __restrict__ bucket_base,
                       int* __restrict__ pk, ushort_t* __restrict__ pw, int E, int chunk) {
    __shared__ int cur[NBUCK];
    int c = blockIdx.x, t = threadIdx.x;
    cur[t] = bucket_base[t] + cntmat[t * NCHUNK + c];
    __syncthreads();
    int lo = c * chunk, hi = min(lo + chunk, E);
    for (int e = lo + t; e < hi; e += 256) {
        int src = ei[e];
        int dst = ei[E + e];
        float w = ew[e];
        int b = (unsigned)dst >> 9;
        int pos = atomicAdd(&cur[b], 1);
        pk[pos] = src | ((dst & 511) << 17);
        pw[pos] = f2b(w);
    }
}

// ---------------- Kernel 5: per-bucket node-sort: write sorted records + offs
__launch_bounds__(256)
__global__ void k_build(const int* __restrict__ pk, const ushort_t* __restrict__ pw,
                        const int* __restrict__ bucket_base, int* __restrict__ sk,
                        ushort_t* __restrict__ sw, int* __restrict__ offs, int n_nodes) {
    __shared__ int h[512];
    __shared__ int psum[256];
    int b = blockIdx.x, t = threadIdx.x;
    int start = bucket_base[b], end = bucket_base[b + 1];
    h[t] = 0; h[t + 256] = 0;
    __syncthreads();
    for (int i = start + t; i < end; i += 256)
        atomicAdd(&h[(unsigned)pk[i] >> 17], 1);
    __syncthreads();
    int h0 = h[2 * t], h1 = h[2 * t + 1];
    int p = h0 + h1;
    psum[t] = p;
    __syncthreads();
    for (int off = 1; off < 256; off <<= 1) {
        int x = psum[t]; int add = (t >= off) ? psum[t - off] : 0;
        __syncthreads(); psum[t] = x + add; __syncthreads();
    }
    int e0 = psum[t] - p;
    int e1 = e0 + h0;
    h[2 * t] = e0; h[2 * t + 1] = e1;
    int node0 = b * 512 + 2 * t;
    if (node0 < n_nodes) offs[node0] = start + e0;
    if (node0 + 1 < n_nodes) offs[node0 + 1] = start + e1;
    __syncthreads();
    for (int i = start + t; i < end; i += 256) {
        int key = pk[i];
        int dl = (unsigned)key >> 17;
        int pos = start + atomicAdd(&h[dl], 1);
        sk[pos] = key;
        sw[pos] = pw[i];
    }
}

// ---------------- Kernel 6: gather-aggregate + residual + LayerNorm (wave per node)
// Gather addressing: row base kept WAVE-UNIFORM (readlane result -> SGPR scalar math,
// saddr-form load); lane offset applied last. Weight unpack also uniform (SALU).
__launch_bounds__(256)
__global__ void k_agg_ln(const ushort_t* __restrict__ support, const int* __restrict__ offs,
                         const int* __restrict__ sk, const ushort_t* __restrict__ sw,
                         const float* __restrict__ gamma, const float* __restrict__ beta,
                         float* __restrict__ out, int n_nodes) {
    int gw = (int)((blockIdx.x * blockDim.x + threadIdx.x) >> 6);
    int lane = threadIdx.x & 63;
    int nw = (int)((gridDim.x * blockDim.x) >> 6);
    float g0 = gamma[lane * 2], g1 = gamma[lane * 2 + 1];
    float b0 = beta[lane * 2], b1 = beta[lane * 2 + 1];

    for (int node = gw; node < n_nodes; node += nw) {
        int start = offs[node], end = offs[node + 1];
        float ax = 0.0f, ay = 0.0f;
        for (int base = start; base < end; base += 64) {
            int n = end - base; if (n > 64) n = 64;
            int key = 0, wb = 0;
            if (lane < n) {
                key = sk[base + lane];
                wb = (int)sw[base + lane];
            }
            int j = 0;
            for (; j + 8 <= n; j += 8) {
                unsigned int v[8]; float w[8];
#pragma unroll
                for (int u = 0; u < 8; u++) {
                    int s = __builtin_amdgcn_readlane(key, j + u) & 131071;   // uniform
                    unsigned int wf = ((unsigned int)__builtin_amdgcn_readlane(wb, j + u)) << 16; // uniform
                    w[u] = __int_as_float(wf);
                    const unsigned int* rowp =
                        (const unsigned int*)(support + (long)s * 128);       // uniform base
                    v[u] = rowp[lane];                                        // saddr + lane off
                }
#pragma unroll
                for (int u = 0; u < 8; u++) {
                    ax += w[u] * b2f((ushort_t)(v[u] & 0xffffu));
                    ay += w[u] * b2f((ushort_t)(v[u] >> 16));
                }
            }
            for (; j < n; j++) {
                int s = __builtin_amdgcn_readlane(key, j) & 131071;
                unsigned int wf = ((unsigned int)__builtin_amdgcn_readlane(wb, j)) << 16;
                float wj = __int_as_float(wf);
                const unsigned int* rowp =
                    (const unsigned int*)(support + (long)s * 128);
                unsigned int v = rowp[lane];
                ax += wj * b2f((ushort_t)(v & 0xffffu));
                ay += wj * b2f((ushort_t)(v >> 16));
            }
        }
        float2 r = *(const float2*)(out + (long)node * 128 + lane * 2);
        float tx = ax + r.x, ty = ay + r.y;
        float s = tx + ty;
        float ss = tx * tx + ty * ty;
#pragma unroll
        for (int off = 1; off < 64; off <<= 1) {
            s += __shfl_xor(s, off, 64);
            ss += __shfl_xor(ss, off, 64);
        }
        float mean = s * (1.0f / 128.0f);
        float var = ss * (1.0f / 128.0f) - mean * mean;
        float rstd = rsqrtf(var + LN_EPS);
        float2 o;
        o.x = (tx - mean) * rstd * g0 + b0;
        o.y = (ty - mean) * rstd * g1 + b1;
        *(float2*)(out + (long)node * 128 + lane * 2) = o;
    }
}

extern "C" void kernel_launch(void* const* d_in, const int* in_sizes, int n_in,
                              void* d_out, int out_size, void* d_ws, size_t ws_size,
                              hipStream_t stream) {
    const float* x      = (const float*)d_in[0];
    const float* weight = (const float*)d_in[1];
    const float* bias   = (const float*)d_in[2];
    const float* res_w  = (const float*)d_in[3];
    const float* res_b  = (const float*)d_in[4];
    const float* gamma  = (const float*)d_in[5];
    const float* beta   = (const float*)d_in[6];
    const float* ew     = (const float*)d_in[7];
    const int*   ei     = (const int*)d_in[8];

    const int E = in_sizes[7];
    const int n_nodes = in_sizes[0] / D_IN;
    const int chunk = (E + NCHUNK - 1) / NCHUNK;
    float* out = (float*)d_out;

    // workspace layout (256B-aligned), total ~65 MB (identical to round-0 verified layout)
    char* ws = (char*)d_ws;
    size_t off = 0;
    auto alloc = [&](size_t bytes) { void* p = ws + off; off = (off + bytes + 255) & ~(size_t)255; return p; };
    ushort_t* wt      = (ushort_t*)alloc(256 * 256 * 2);                 // 128 KB
    ushort_t* support = (ushort_t*)alloc((size_t)n_nodes * 128 * 2);     // 25.6 MB
    int* cntmat       = (int*)alloc((size_t)NBUCK * NCHUNK * 4);         // 256 KB
    int* rowsum       = (int*)alloc(NBUCK * 4);
    int* bucket_base  = (int*)alloc((NBUCK + 1) * 4);
    int* offs         = (int*)alloc((size_t)(n_nodes + 1) * 4);          // 400 KB
    int* pk           = (int*)alloc((size_t)E * 4);                      // 12.8 MB
    ushort_t* pw      = (ushort_t*)alloc((size_t)E * 2);                 // 6.4 MB
    int* sk           = (int*)alloc((size_t)E * 4);                      // 12.8 MB
    ushort_t* sw      = (ushort_t*)alloc((size_t)E * 2);                 // 6.4 MB

    k_transpose<<<256, 256, 0, stream>>>(weight, res_w, wt);
    k_gemm<<<(n_nodes + 63) / 64, 256, 0, stream>>>(x, wt, bias, res_b, support, out, n_nodes);
    k_count<<<NCHUNK, 256, 0, stream>>>(ei, cntmat, E, chunk);
    k_scan1<<<NBUCK, 256, 0, stream>>>(cntmat, rowsum);
    k_scan2<<<1, 256, 0, stream>>>(rowsum, bucket_base, offs, n_nodes, E);
    k_part<<<NCHUNK, 256, 0, stream>>>(ei, ew, cntmat, bucket_base, pk, pw, E, chunk);
    k_build<<<NBUCK, 256, 0, stream>>>(pk, pw, bucket_base, sk, sw, offs, n_nodes);
    k_agg_ln<<<4096, 256, 0, stream>>>(support, offs, sk, sw, gamma, beta, out, n_nodes);
}